// Round 18
// baseline (2284.969 us; speedup 1.0000x reference)
//
#include <hip/hip_runtime.h>
#include <hip/hip_fp16.h>
#include <math.h>

#define NN 50000
#define EE 800000
#define LL 4

typedef unsigned short u16;
typedef unsigned int u32;
typedef __attribute__((ext_vector_type(8))) short bf16x8;
typedef __attribute__((ext_vector_type(4))) float f32x4;

__device__ __forceinline__ float rlane(float v, int l) {
  return __int_as_float(__builtin_amdgcn_readlane(__float_as_int(v), l));
}
__device__ __forceinline__ u32 rlane_u32(u32 v, int l) {
  return (u32)__builtin_amdgcn_readlane((int)v, l);
}

__device__ __forceinline__ float matvec64(float xv, const float* __restrict__ w) {
  float a0 = 0.f, a1 = 0.f, a2 = 0.f, a3 = 0.f;
#pragma unroll
  for (int k = 0; k < 64; k += 4) {
    a0 = fmaf(rlane(xv, k + 0), w[k + 0], a0);
    a1 = fmaf(rlane(xv, k + 1), w[k + 1], a1);
    a2 = fmaf(rlane(xv, k + 2), w[k + 2], a2);
    a3 = fmaf(rlane(xv, k + 3), w[k + 3], a3);
  }
  return (a0 + a1) + (a2 + a3);
}

__device__ __forceinline__ float sigm(float x) { return 1.f / (1.f + __expf(-x)); }

__device__ __forceinline__ u16 f2b(float x) {
  u32 u = __float_as_uint(x);
  u32 r = (u + 0x7FFFu + ((u >> 16) & 1u)) >> 16;
  return (u16)r;
}
__device__ __forceinline__ float b2f(u16 b) { return __uint_as_float(((u32)b) << 16); }

__device__ __forceinline__ u16 f2h_(float x) {
  __half h = __float2half_rn(x);
  return *(u16*)&h;
}
__device__ __forceinline__ float h2f_(u16 b) {
  __half h = *(__half*)&b;
  return __half2float(h);
}

// ---------------- MFMA helpers (node-parallel, 16 nodes per wave) -----------
struct FragA { bf16x8 hi0, hi1, lo0, lo1; };

__device__ __forceinline__ void load_a(const float* __restrict__ base, int l, FragA& fa) {
  const int row = l & 15, quad = l >> 4;
  const float* src = base + (size_t)row * 64 + quad * 8;
  bf16x8 h0, h1, l0, l1;
#pragma unroll
  for (int j = 0; j < 8; ++j) {
    float x0 = src[j], x1 = src[32 + j];
    u16 a0 = f2b(x0), a1 = f2b(x1);
    h0[j] = (short)a0; h1[j] = (short)a1;
    l0[j] = (short)f2b(x0 - b2f(a0));
    l1[j] = (short)f2b(x1 - b2f(a1));
  }
  fa.hi0 = h0; fa.hi1 = h1; fa.lo0 = l0; fa.lo1 = l1;
}

__device__ __forceinline__ void gemm_acc(const FragA& fa, const float* __restrict__ W,
                                         int l, f32x4 acc[4]) {
  const int row = l & 15, quad = l >> 4;
#pragma unroll
  for (int cb = 0; cb < 4; ++cb) {
    f32x4 z = acc[cb];
#pragma unroll
    for (int kb = 0; kb < 2; ++kb) {
      bf16x8 bhi, blo;
      const float* wp = W + (size_t)(kb * 32 + quad * 8) * 64 + cb * 16 + row;
#pragma unroll
      for (int j = 0; j < 8; ++j) {
        float wv = wp[(size_t)j * 64];
        u16 aa = f2b(wv);
        bhi[j] = (short)aa;
        blo[j] = (short)f2b(wv - b2f(aa));
      }
      const bf16x8 ahi = kb ? fa.hi1 : fa.hi0;
      const bf16x8 alo = kb ? fa.lo1 : fa.lo0;
      z = __builtin_amdgcn_mfma_f32_16x16x32_bf16(ahi, bhi, z, 0, 0, 0);
      z = __builtin_amdgcn_mfma_f32_16x16x32_bf16(alo, bhi, z, 0, 0, 0);
      z = __builtin_amdgcn_mfma_f32_16x16x32_bf16(ahi, blo, z, 0, 0, 0);
    }
    acc[cb] = z;
  }
}

__device__ __forceinline__ void store16(const f32x4 acc[4], const float* __restrict__ bias,
                                        int l, float* __restrict__ out) {
  const int row = l & 15, quad = l >> 4;
#pragma unroll
  for (int cb = 0; cb < 4; ++cb) {
    int col = cb * 16 + row;
    float bv = bias[col];
#pragma unroll
    for (int r = 0; r < 4; ++r)
      out[(size_t)(quad * 4 + r) * 64 + col] = acc[cb][r] + bv;
  }
}

__global__ void k_t2(const float* __restrict__ h, const float* __restrict__ B1w,
                     int* __restrict__ flag) {
  int l = threadIdx.x;
  FragA fa;
  load_a(h, l, fa);
  f32x4 acc[4];
  acc[0] = (f32x4){0,0,0,0}; acc[1] = (f32x4){0,0,0,0};
  acc[2] = (f32x4){0,0,0,0}; acc[3] = (f32x4){0,0,0,0};
  gemm_acc(fa, B1w, l, acc);
  const int row = l & 15, quad = l >> 4;
  int ok = 1;
#pragma unroll
  for (int cb = 0; cb < 4; ++cb)
#pragma unroll
    for (int r = 0; r < 4; ++r) {
      int nrow = quad * 4 + r, col = cb * 16 + row;
      float ref = 0.f;
      for (int k = 0; k < 64; ++k) ref += h[nrow * 64 + k] * B1w[k * 64 + col];
      if (fabsf(acc[cb][r] - ref) > 3e-3f + 3e-3f * fabsf(ref)) ok = 0;
    }
  ok = __all(ok);
  if (l == 0) flag[0] = ok;
}

// ---------------- CSR build ----------------
__global__ void k_hist(const int* __restrict__ dst, int* __restrict__ counts) {
  int i = blockIdx.x * 256 + threadIdx.x;
  if (i < EE) atomicAdd(&counts[dst[i]], 1);
}

__global__ void k_scan(const int* __restrict__ counts, int* __restrict__ row_start,
                       int* __restrict__ cursor) {
  __shared__ int sd[1024];
  int tid = threadIdx.x;
  int running = 0;
  for (int basei = 0; basei < NN; basei += 1024) {
    int i = basei + tid;
    int v = (i < NN) ? counts[i] : 0;
    sd[tid] = v;
    __syncthreads();
    for (int ofs = 1; ofs < 1024; ofs <<= 1) {
      int t = (tid >= ofs) ? sd[tid - ofs] : 0;
      __syncthreads();
      sd[tid] += t;
      __syncthreads();
    }
    int incl = sd[tid];
    int total = sd[1023];
    if (i < NN) { int e = running + incl - v; row_start[i] = e; cursor[i] = e; }
    running += total;
    __syncthreads();
  }
  if (tid == 0) row_start[NN] = EE;
}

__global__ void k_scatter(const int* __restrict__ dst, const int* __restrict__ src,
                          const int* __restrict__ e_ids,
                          int* __restrict__ cursor, int* __restrict__ src_s,
                          int* __restrict__ eids_s) {
  int i = blockIdx.x * 256 + threadIdx.x;
  if (i < EE) {
    int d = dst[i];
    int pos = atomicAdd(&cursor[d], 1);
    src_s[pos] = src[i];
    eids_s[pos] = e_ids[i];
  }
}

__global__ void k_einit(const int* __restrict__ eids_s, const float* __restrict__ emb_e,
                        u16* __restrict__ e_sorted) {
  int idx = blockIdx.x * 256 + threadIdx.x;
  if (idx >= EE * 64) return;
  int ed = idx >> 6, f = idx & 63;
  e_sorted[idx] = f2h_(emb_e[eids_s[ed] * 64 + f]);
}

__global__ void k_ninit(const int* __restrict__ h_ids, const int* __restrict__ f_ids,
                        const float* __restrict__ emb_h, const float* __restrict__ emb_f,
                        float* __restrict__ h, float* __restrict__ p) {
  int idx = blockIdx.x * 256 + threadIdx.x;
  if (idx >= NN * 64) return;
  int n = idx >> 6, f = idx & 63;
  h[idx] = emb_h[h_ids[n] * 64 + f];
  p[idx] = emb_f[f_ids[n] * 64 + f];
}

// ---------------- k_Am: MFMA node GEMMs (runs iff flag=1) -------------------
// vbuf & C2p now interleaved into vc[n][f] = float2{v, c2p} (one 8B gather
// in k_C instead of two 4B gathers).
__global__ void __launch_bounds__(256) k_Am(
    int mode,
    float* __restrict__ h, float* __restrict__ p,
    float* __restrict__ hn, float* __restrict__ pn,
    const float* __restrict__ mu_h, const float* __restrict__ ir_h,
    const float* __restrict__ g_h, const float* __restrict__ b_h,
    const float* __restrict__ B1w, const float* __restrict__ B1b,
    const float* __restrict__ B2w, const float* __restrict__ B2b,
    const float* __restrict__ A1w, const float* __restrict__ A1b,
    const float* __restrict__ C1w, const float* __restrict__ C1b,
    const float* __restrict__ C2w, const float* __restrict__ C2b,
    const float* __restrict__ A2w, const float* __restrict__ A2b,
    float* __restrict__ B1h, float* __restrict__ B2h,
    float* __restrict__ vc,
    const int* __restrict__ flag) {
  if (!flag[0]) return;
  const int f = threadIdx.x & 63;
  const int wv = threadIdx.x >> 6;
  const int base0 = (blockIdx.x * 4 + wv) * 16;
  if (base0 >= NN) return;

  if (mode) {
    float mu = mu_h[f], ir = ir_h[f], ga = g_h[f], be = b_h[f];
    for (int i = 0; i < 16; ++i) {
      int n = base0 + i;
      float hv = hn[(size_t)n * 64 + f];
      h[(size_t)n * 64 + f] += fmaxf(0.f, (hv - mu) * ir * ga + be);
      float pv = pn[(size_t)n * 64 + f];
      p[(size_t)n * 64 + f] += tanhf(pv);
    }
  }

  FragA fh, fq;
  load_a(h + (size_t)base0 * 64, f, fh);
  load_a(p + (size_t)base0 * 64, f, fq);
  f32x4 acc[4], accC[4];
#define ZERO(A) { A[0]=(f32x4){0,0,0,0}; A[1]=(f32x4){0,0,0,0}; \
                  A[2]=(f32x4){0,0,0,0}; A[3]=(f32x4){0,0,0,0}; }
  ZERO(acc); gemm_acc(fh, B1w, f, acc); store16(acc, B1b, f, B1h + (size_t)base0 * 64);
  ZERO(acc); gemm_acc(fh, B2w, f, acc); store16(acc, B2b, f, B2h + (size_t)base0 * 64);
  ZERO(acc); gemm_acc(fh, A1w, f, acc); store16(acc, A1b, f, hn + (size_t)base0 * 64);
  ZERO(acc); gemm_acc(fq, C1w, f, acc); store16(acc, C1b, f, pn + (size_t)base0 * 64);
  ZERO(accC); gemm_acc(fq, C2w, f, accC);                       // C2p
  ZERO(acc);  gemm_acc(fh, A2w, f, acc); gemm_acc(fq, A2w + 4096, f, acc);  // v
  {
    const int row = f & 15, quad = f >> 4;
    float2* out = (float2*)vc;
#pragma unroll
    for (int cb = 0; cb < 4; ++cb) {
      int col = cb * 16 + row;
      float bv = A2b[col], cv = C2b[col];
#pragma unroll
      for (int r = 0; r < 4; ++r) {
        float2 val;
        val.x = acc[cb][r] + bv;
        val.y = accC[cb][r] + cv;
        out[(size_t)(base0 + quad * 4 + r) * 64 + col] = val;
      }
    }
  }
#undef ZERO
}

// ---------------- k_Av: readlane fallback (runs iff flag=0) -----------------
__global__ void __launch_bounds__(256) k_Av(
    int mode,
    float* __restrict__ h, float* __restrict__ p,
    float* __restrict__ hn, float* __restrict__ pn,
    const float* __restrict__ mu_h, const float* __restrict__ ir_h,
    const float* __restrict__ g_h, const float* __restrict__ b_h,
    const float* __restrict__ B1w, const float* __restrict__ B1b,
    const float* __restrict__ B2w, const float* __restrict__ B2b,
    const float* __restrict__ A1w, const float* __restrict__ A1b,
    const float* __restrict__ C1w, const float* __restrict__ C1b,
    const float* __restrict__ C2w, const float* __restrict__ C2b,
    const float* __restrict__ A2w, const float* __restrict__ A2b,
    float* __restrict__ B1h, float* __restrict__ B2h,
    float* __restrict__ vc,
    const int* __restrict__ flag) {
  if (flag[0]) return;
  const int f = threadIdx.x & 63;
  const int wv = threadIdx.x >> 6;
  const int base0 = (blockIdx.x * 4 + wv) * 16;
  if (base0 >= NN) return;

  if (mode) {
    float mu = mu_h[f], ir = ir_h[f], ga = g_h[f], be = b_h[f];
    for (int i = 0; i < 16; ++i) {
      int n = base0 + i;
      float hv = hn[n * 64 + f];
      h[n * 64 + f] += fmaxf(0.f, (hv - mu) * ir * ga + be);
      float pv = pn[n * 64 + f];
      p[n * 64 + f] += tanhf(pv);
    }
  }

  float w[64];
#define LOADW(WP) _Pragma("unroll") for (int k = 0; k < 64; ++k) w[k] = (WP)[k * 64 + f];
  LOADW(B1w);
  { float bb = B1b[f];
    for (int i = 0; i < 16; ++i) { int n = base0 + i;
      B1h[n * 64 + f] = matvec64(h[n * 64 + f], w) + bb; } }
  LOADW(B2w);
  { float bb = B2b[f];
    for (int i = 0; i < 16; ++i) { int n = base0 + i;
      B2h[n * 64 + f] = matvec64(h[n * 64 + f], w) + bb; } }
  LOADW(A1w);
  { float bb = A1b[f];
    for (int i = 0; i < 16; ++i) { int n = base0 + i;
      hn[n * 64 + f] = matvec64(h[n * 64 + f], w) + bb; } }
  LOADW(C1w);
  { float bb = C1b[f];
    for (int i = 0; i < 16; ++i) { int n = base0 + i;
      pn[n * 64 + f] = matvec64(p[n * 64 + f], w) + bb; } }
  LOADW(C2w);
  { float bb = C2b[f];
    for (int i = 0; i < 16; ++i) { int n = base0 + i;
      vc[((size_t)n * 64 + f) * 2 + 1] = matvec64(p[n * 64 + f], w) + bb; } }
  {
    float w2[64];
#pragma unroll
    for (int k = 0; k < 64; ++k) { w[k] = A2w[k * 64 + f]; w2[k] = A2w[(k + 64) * 64 + f]; }
    float bb = A2b[f];
    for (int i = 0; i < 16; ++i) { int n = base0 + i;
      vc[((size_t)n * 64 + f) * 2] =
          matvec64(h[n * 64 + f], w) + matvec64(p[n * 64 + f], w2) + bb; }
  }
#undef LOADW
}

// k_B: hat = e@B3 + B1h[src] + B2h[dst] + b3 ; sigma row-sum; BN-e stats.
// Packed-f16 __hfma2 matvec. MODE: 0 none; 1 deferred e-update + write;
// 2 deferred e-update in-register only (layer 3).
template <int SH, int MODE>
__global__ void __launch_bounds__(256) k_B(
    u16* __restrict__ e16, const float* __restrict__ B1h,
    const float* __restrict__ B2h, const int* __restrict__ src_s,
    const int* __restrict__ row_start,
    const float* __restrict__ B3w, const float* __restrict__ B3b,
    const float* __restrict__ mu_p, const float* __restrict__ ir_p,
    const float* __restrict__ g_p, const float* __restrict__ b_p,
    u16* __restrict__ hat, float* __restrict__ sum_sigma,
    float* __restrict__ eS1, float* __restrict__ eS2) {
  const int f = threadIdx.x & 63;
  const int wv = threadIdx.x >> 6;
  const int nb = (blockIdx.x * 4 + wv) * 4;
  if (nb >= NN) return;
  const int kk = f & 31;

  __half2 wpk[32];
#pragma unroll
  for (int k = 0; k < 32; ++k) {
    float w0 = B3w[(size_t)(2 * k) * 64 + f];
    float w1 = B3w[(size_t)(2 * k + 1) * 64 + f];
    wpk[k] = __floats2half2_rn(w0, w1);
  }
  const float bb = B3b[f];
  float a0 = 0.f, c0 = 0.f, a1 = 0.f, c1 = 0.f;
  if (MODE >= 1) {
    float m0 = mu_p[2 * kk], i0 = ir_p[2 * kk];
    float m1 = mu_p[2 * kk + 1], i1 = ir_p[2 * kk + 1];
    a0 = i0 * g_p[2 * kk];     c0 = b_p[2 * kk] - m0 * a0;
    a1 = i1 * g_p[2 * kk + 1]; c1 = b_p[2 * kk + 1] - m1 * a1;
  }
  float s1 = 0.f, s2 = 0.f;
  for (int i = 0; i < 4; ++i) {
    int n = nb + i;
    float b2 = B2h[(size_t)n * 64 + f] + bb;
    float ssum = 0.f;
    int t0 = row_start[n], t1 = row_start[n + 1];
    for (int t = t0; t < t1; ++t) {
      u32 xq = ((const u32*)e16)[(size_t)t * 32 + kk];
      if (MODE >= 1) {
        if (f < 32) {
          u32 hq = ((const u32*)hat)[(size_t)t * 32 + kk];
          float p0 = __uint_as_float(hq << 16);
          float p1 = __uint_as_float(hq & 0xffff0000u);
          __half2 ex = *(__half2*)&xq;
          float e0 = __low2float(ex)  + fmaxf(0.f, fmaf(p0, a0, c0));
          float e1 = __high2float(ex) + fmaxf(0.f, fmaf(p1, a1, c1));
          __half2 nq = __floats2half2_rn(e0, e1);
          xq = *(u32*)&nq;
          if (MODE == 1) ((u32*)e16)[(size_t)t * 32 + kk] = xq;
        }
      }
      int s = src_s[t];
      float g = B1h[(size_t)s * 64 + f];
      __half2 za = __float2half2_rn(0.f), zb = za, zc = za, zd = za;
#pragma unroll
      for (int k = 0; k < 32; k += 4) {
        u32 q0 = rlane_u32(xq, k + 0);
        u32 q1 = rlane_u32(xq, k + 1);
        u32 q2 = rlane_u32(xq, k + 2);
        u32 q3 = rlane_u32(xq, k + 3);
        za = __hfma2(*(__half2*)&q0, wpk[k + 0], za);
        zb = __hfma2(*(__half2*)&q1, wpk[k + 1], zb);
        zc = __hfma2(*(__half2*)&q2, wpk[k + 2], zc);
        zd = __hfma2(*(__half2*)&q3, wpk[k + 3], zd);
      }
      float dot = ((__low2float(za) + __high2float(za)) +
                   (__low2float(zb) + __high2float(zb))) +
                  ((__low2float(zc) + __high2float(zc)) +
                   (__low2float(zd) + __high2float(zd)));
      float acc = dot + b2 + g;
      if (SH) {
        u16 hb = f2b(acc);
        hat[(size_t)t * 64 + f] = hb;
        acc = b2f(hb);
      }
      float sg = sigm(acc);
      ssum += sg; s1 += acc; s2 += acc * acc;
    }
    sum_sigma[(size_t)n * 64 + f] = ssum;
  }
  int slot = (blockIdx.x & 255) * 64 + f;
  atomicAdd(&eS1[slot], s1);
  atomicAdd(&eS2[slot], s2);
}

__global__ void k_red(const float* __restrict__ S1, const float* __restrict__ S2,
                      float cnt, float* __restrict__ mu, float* __restrict__ ir) {
  int f = threadIdx.x;
  float a = 0.f, b = 0.f;
  for (int j = 0; j < 256; ++j) { a += S1[j * 64 + f]; b += S2[j * 64 + f]; }
  float m = a / cnt;
  float var = fmaxf(b / cnt - m * m, 0.f);
  mu[f] = m;
  ir[f] = rsqrtf(var + 1e-5f);
}

// k_C: eta, single float2 gather per (edge,feature), BN-h stats. (1 node/wave)
template <int SH, int LAST>
__global__ void __launch_bounds__(256) k_C(
    const u16* __restrict__ hat, u16* __restrict__ e_sorted,
    const float* __restrict__ B1h, const float* __restrict__ B2h,
    const float* __restrict__ B3w, const float* __restrict__ B3b,
    const float* __restrict__ vc,
    const int* __restrict__ src_s, const int* __restrict__ row_start,
    const float* __restrict__ sum_sigma,
    float* __restrict__ hn, float* __restrict__ pn,
    const float* __restrict__ mu_e, const float* __restrict__ ir_e,
    const float* __restrict__ g_e, const float* __restrict__ b_e,
    float* __restrict__ hS1, float* __restrict__ hS2) {
  const int f = threadIdx.x & 63;
  const int wv = threadIdx.x >> 6;
  const int n = blockIdx.x * 4 + wv;
  if (n >= NN) return;
  const float2* vcp = (const float2*)vc;
  float w[64];
  float bb = 0.f;
  if (!SH) {
#pragma unroll
    for (int k = 0; k < 64; ++k) w[k] = B3w[k * 64 + f];
    bb = B3b[f];
  }
  float mu = mu_e[f], ir = ir_e[f], ga = g_e[f], be = b_e[f];
  float inv = 1.f / (sum_sigma[n * 64 + f] + 1e-6f);
  float ahv = 0.f, ahp = 0.f;
  int t0 = row_start[n], t1 = row_start[n + 1];
  int t = t0;
  if (SH) {
    for (; t + 4 <= t1; t += 4) {
      size_t s0 = (size_t)src_s[t + 0] * 64 + f, s1 = (size_t)src_s[t + 1] * 64 + f;
      size_t s2 = (size_t)src_s[t + 2] * 64 + f, s3 = (size_t)src_s[t + 3] * 64 + f;
      float hv0 = b2f(hat[(size_t)(t + 0) * 64 + f]);
      float hv1 = b2f(hat[(size_t)(t + 1) * 64 + f]);
      float hv2 = b2f(hat[(size_t)(t + 2) * 64 + f]);
      float hv3 = b2f(hat[(size_t)(t + 3) * 64 + f]);
      float2 q0 = vcp[s0], q1 = vcp[s1], q2 = vcp[s2], q3 = vcp[s3];
      float et0 = sigm(hv0) * inv, et1 = sigm(hv1) * inv;
      float et2 = sigm(hv2) * inv, et3 = sigm(hv3) * inv;
      ahv += et0 * q0.x + et1 * q1.x + et2 * q2.x + et3 * q3.x;
      if (!LAST)
        ahp += et0 * q0.y + et1 * q1.y + et2 * q2.y + et3 * q3.y;
    }
  }
  for (; t < t1; ++t) {
    size_t s = (size_t)src_s[t] * 64 + f;
    float ev = 0.f;
    if (!SH) ev = h2f_(e_sorted[(size_t)t * 64 + f]);
    float hatv;
    if (SH) hatv = b2f(hat[(size_t)t * 64 + f]);
    else    hatv = matvec64(ev, w) + bb + B2h[n * 64 + f] + B1h[((size_t)src_s[t]) * 64 + f];
    float eta = sigm(hatv) * inv;
    float2 q = vcp[s];
    ahv = fmaf(eta, q.x, ahv);
    if (!LAST) {
      ahp = fmaf(eta, q.y, ahp);
      if (!SH)
        e_sorted[(size_t)t * 64 + f] = f2h_(ev + fmaxf(0.f, (hatv - mu) * ir * ga + be));
    }
  }
  float hv = hn[n * 64 + f] + ahv; hn[n * 64 + f] = hv;
  if (!LAST) pn[n * 64 + f] += ahp;
  int slot = (blockIdx.x & 255) * 64 + f;
  atomicAdd(&hS1[slot], hv);
  atomicAdd(&hS2[slot], hv * hv);
}

__global__ void __launch_bounds__(256) k_F1(
    const float* __restrict__ hn, const float* __restrict__ h,
    const float* __restrict__ mu, const float* __restrict__ ir,
    const float* __restrict__ ga, const float* __restrict__ be,
    float* __restrict__ hsum) {
  int f = threadIdx.x & 63, wv = threadIdx.x >> 6;
  float m = mu[f], r = ir[f], g = ga[f], b = be[f];
  float ps = 0.f;
  for (int n = blockIdx.x * 4 + wv; n < NN; n += gridDim.x * 4)
    ps += h[n * 64 + f] + fmaxf(0.f, (hn[n * 64 + f] - m) * r * g + b);
  atomicAdd(&hsum[f], ps);
}

__global__ void k_F2(const float* __restrict__ hsum,
                     const float* __restrict__ w0, const float* __restrict__ b0,
                     const float* __restrict__ w1, const float* __restrict__ b1,
                     const float* __restrict__ w2, const float* __restrict__ b2,
                     float* __restrict__ out) {
  __shared__ float hg[64]; __shared__ float y0[32]; __shared__ float y1[16];
  int t = threadIdx.x;
  hg[t] = hsum[t] * (1.f / (float)NN);
  __syncthreads();
  if (t < 32) { float a = b0[t];
    for (int k = 0; k < 64; ++k) a = fmaf(hg[k], w0[k * 32 + t], a);
    y0[t] = fmaxf(a, 0.f); }
  __syncthreads();
  if (t < 16) { float a = b1[t];
    for (int k = 0; k < 32; ++k) a = fmaf(y0[k], w1[k * 16 + t], a);
    y1[t] = fmaxf(a, 0.f); }
  __syncthreads();
  if (t == 0) { float a = b2[0];
    for (int k = 0; k < 16; ++k) a = fmaf(y1[k], w2[k], a);
    out[0] = a; }
}

__global__ void k_report(float* out, float v) { out[0] = v; }

extern "C" void kernel_launch(void* const* d_in, const int* in_sizes, int n_in,
                              void* d_out, int out_size, void* d_ws, size_t ws_size,
                              hipStream_t stream) {
  (void)in_sizes; (void)n_in; (void)out_size;
  const int* h_ids = (const int*)d_in[0];
  const int* e_ids = (const int*)d_in[1];
  const int* f_ids = (const int*)d_in[2];
  const int* src   = (const int*)d_in[3];
  const int* dst   = (const int*)d_in[4];
  const float* emb_h = (const float*)d_in[5];
  const float* emb_e = (const float*)d_in[6];
  const float* emb_f = (const float*)d_in[7];
  const float* A1_w = (const float*)d_in[8];  const float* A1_b = (const float*)d_in[9];
  const float* A2_w = (const float*)d_in[10]; const float* A2_b = (const float*)d_in[11];
  const float* B1_w = (const float*)d_in[12]; const float* B1_b = (const float*)d_in[13];
  const float* B2_w = (const float*)d_in[14]; const float* B2_b = (const float*)d_in[15];
  const float* B3_w = (const float*)d_in[16]; const float* B3_b = (const float*)d_in[17];
  const float* C1_w = (const float*)d_in[18]; const float* C1_b = (const float*)d_in[19];
  const float* C2_w = (const float*)d_in[20]; const float* C2_b = (const float*)d_in[21];
  const float* bn_h_g = (const float*)d_in[22]; const float* bn_h_b = (const float*)d_in[23];
  const float* bn_e_g = (const float*)d_in[24]; const float* bn_e_b = (const float*)d_in[25];
  const float* mlp_w0 = (const float*)d_in[26]; const float* mlp_b0 = (const float*)d_in[27];
  const float* mlp_w1 = (const float*)d_in[28]; const float* mlp_b1 = (const float*)d_in[29];
  const float* mlp_w2 = (const float*)d_in[30]; const float* mlp_b2 = (const float*)d_in[31];

  auto pad = [](size_t b) { return (b + 255) & ~(size_t)255; };
  const size_t sz_e    = pad((size_t)EE * 64 * 2);   // f16 edge state
  const size_t sz_node = pad((size_t)NN * 64 * 4);   // fp32 node buffer
  const size_t sz_cnt  = pad((size_t)NN * 4);
  const size_t sz_row  = pad((size_t)(NN + 1) * 4);
  const size_t sz_ei   = pad((size_t)EE * 4);
  const size_t sz_stat = pad((size_t)LL * 2 * 256 * 64 * 4);
  const size_t sz_vec  = pad(64 * 4);

  size_t base_need = sz_e + 9 * sz_node + 2 * sz_cnt + sz_row + 2 * sz_ei +
                     2 * sz_stat + 6 * sz_vec;
  bool store_hat = (base_need + sz_e) <= ws_size;
  if (base_need > ws_size) {
    k_report<<<1, 1, 0, stream>>>((float*)d_out, (float)(ws_size >> 20) + 0.125f);
    return;
  }

  char* cur = (char*)d_ws;
  auto alloc = [&](size_t bytes) -> char* { char* r = cur; cur += bytes; return r; };
  u16* e_sorted = (u16*)alloc(sz_e);
  u16* hat      = store_hat ? (u16*)alloc(sz_e) : (u16*)e_sorted;  // dummy if unused
  float* h    = (float*)alloc(sz_node);
  float* p    = (float*)alloc(sz_node);
  float* hn   = (float*)alloc(sz_node);
  float* pn   = (float*)alloc(sz_node);
  float* B1h  = (float*)alloc(sz_node);
  float* B2h  = (float*)alloc(sz_node);
  float* vc   = (float*)alloc(2 * sz_node);   // interleaved {v, C2p}
  float* ssig = (float*)alloc(sz_node);
  int* counts    = (int*)alloc(sz_cnt);
  int* cursor    = (int*)alloc(sz_cnt);
  int* row_start = (int*)alloc(sz_row);
  int* src_s     = (int*)alloc(sz_ei);
  int* eids_s    = (int*)alloc(sz_ei);
  float* estats = (float*)alloc(sz_stat);
  float* hstats = (float*)alloc(sz_stat);
  float* hsum   = (float*)alloc(sz_vec);
  float* mu_h = (float*)alloc(sz_vec);
  float* ir_h = (float*)alloc(sz_vec);
  float* mu_e = (float*)alloc(sz_vec);
  float* ir_e = (float*)alloc(sz_vec);
  int* flag  = (int*)alloc(sz_vec);

  hipMemsetAsync(counts, 0, sz_cnt, stream);
  hipMemsetAsync(estats, 0, 2 * sz_stat + sz_vec, stream);  // estats + hstats + hsum

  k_hist<<<(EE + 255) / 256, 256, 0, stream>>>(dst, counts);
  k_scan<<<1, 1024, 0, stream>>>(counts, row_start, cursor);
  k_scatter<<<(EE + 255) / 256, 256, 0, stream>>>(dst, src, e_ids, cursor, src_s, eids_s);
  k_einit<<<(EE * 64) / 256, 256, 0, stream>>>(eids_s, emb_e, e_sorted);
  k_ninit<<<(NN * 64 + 255) / 256, 256, 0, stream>>>(h_ids, f_ids, emb_h, emb_f, h, p);
  k_t2<<<1, 64, 0, stream>>>(h, B1_w, flag);

  const int STAT = 2 * 256 * 64;
  const int GB = (NN + 15) / 16, GC = (NN + 3) / 4;
  for (int i = 0; i < LL; ++i) {
    if (i > 0) {
      k_red<<<1, 64, 0, stream>>>(hstats + (i - 1) * STAT,
                                  hstats + (i - 1) * STAT + 256 * 64, (float)NN, mu_h, ir_h);
    }
    const float* gh = bn_h_g + (i > 0 ? (i - 1) * 64 : 0);
    const float* bh = bn_h_b + (i > 0 ? (i - 1) * 64 : 0);
    k_Am<<<(NN + 63) / 64, 256, 0, stream>>>(
        (i > 0) ? 1 : 0, h, p, hn, pn, mu_h, ir_h, gh, bh,
        B1_w + i * 4096, B1_b + i * 64, B2_w + i * 4096, B2_b + i * 64,
        A1_w + i * 4096, A1_b + i * 64, C1_w + i * 4096, C1_b + i * 64,
        C2_w + i * 4096, C2_b + i * 64, A2_w + i * 8192, A2_b + i * 64,
        B1h, B2h, vc, flag);
    k_Av<<<(NN + 63) / 64, 256, 0, stream>>>(
        (i > 0) ? 1 : 0, h, p, hn, pn, mu_h, ir_h, gh, bh,
        B1_w + i * 4096, B1_b + i * 64, B2_w + i * 4096, B2_b + i * 64,
        A1_w + i * 4096, A1_b + i * 64, C1_w + i * 4096, C1_b + i * 64,
        C2_w + i * 4096, C2_b + i * 64, A2_w + i * 8192, A2_b + i * 64,
        B1h, B2h, vc, flag);
    const float* gp = bn_e_g + (i > 0 ? (i - 1) * 64 : 0);
    const float* bp = bn_e_b + (i > 0 ? (i - 1) * 64 : 0);
    if (store_hat) {
      if (i == 0)
        k_B<1, 0><<<GB, 256, 0, stream>>>(
            e_sorted, B1h, B2h, src_s, row_start, B3_w + i * 4096, B3_b + i * 64,
            mu_e, ir_e, gp, bp, hat, ssig,
            estats + i * STAT, estats + i * STAT + 256 * 64);
      else if (i < LL - 1)
        k_B<1, 1><<<GB, 256, 0, stream>>>(
            e_sorted, B1h, B2h, src_s, row_start, B3_w + i * 4096, B3_b + i * 64,
            mu_e, ir_e, gp, bp, hat, ssig,
            estats + i * STAT, estats + i * STAT + 256 * 64);
      else
        k_B<1, 2><<<GB, 256, 0, stream>>>(
            e_sorted, B1h, B2h, src_s, row_start, B3_w + i * 4096, B3_b + i * 64,
            mu_e, ir_e, gp, bp, hat, ssig,
            estats + i * STAT, estats + i * STAT + 256 * 64);
    } else {
      k_B<0, 0><<<GB, 256, 0, stream>>>(
          e_sorted, B1h, B2h, src_s, row_start, B3_w + i * 4096, B3_b + i * 64,
          mu_e, ir_e, gp, bp, hat, ssig,
          estats + i * STAT, estats + i * STAT + 256 * 64);
    }
    if (!store_hat || i < LL - 1)
      k_red<<<1, 64, 0, stream>>>(estats + i * STAT, estats + i * STAT + 256 * 64,
                                  (float)EE, mu_e, ir_e);
    bool lastL = (i == LL - 1);
    if (store_hat) {
      if (lastL)
        k_C<1, 1><<<GC, 256, 0, stream>>>(
            hat, e_sorted, B1h, B2h, B3_w + i * 4096, B3_b + i * 64, vc,
            src_s, row_start, ssig, hn, pn, mu_e, ir_e,
            bn_e_g + i * 64, bn_e_b + i * 64,
            hstats + i * STAT, hstats + i * STAT + 256 * 64);
      else
        k_C<1, 0><<<GC, 256, 0, stream>>>(
            hat, e_sorted, B1h, B2h, B3_w + i * 4096, B3_b + i * 64, vc,
            src_s, row_start, ssig, hn, pn, mu_e, ir_e,
            bn_e_g + i * 64, bn_e_b + i * 64,
            hstats + i * STAT, hstats + i * STAT + 256 * 64);
    } else {
      k_C<0, 0><<<GC, 256, 0, stream>>>(
          hat, e_sorted, B1h, B2h, B3_w + i * 4096, B3_b + i * 64, vc,
          src_s, row_start, ssig, hn, pn, mu_e, ir_e,
          bn_e_g + i * 64, bn_e_b + i * 64,
          hstats + i * STAT, hstats + i * STAT + 256 * 64);
    }
  }
  k_red<<<1, 64, 0, stream>>>(hstats + 3 * STAT, hstats + 3 * STAT + 256 * 64,
                              (float)NN, mu_h, ir_h);
  k_F1<<<512, 256, 0, stream>>>(hn, h, mu_h, ir_h, bn_h_g + 3 * 64, bn_h_b + 3 * 64, hsum);
  k_F2<<<1, 64, 0, stream>>>(hsum, mlp_w0, mlp_b0, mlp_w1, mlp_b1, mlp_w2, mlp_b2,
                             (float*)d_out);
}

// Round 19
// 2251.890 us; speedup vs baseline: 1.0147x; 1.0147x over previous
//
#include <hip/hip_runtime.h>
#include <hip/hip_fp16.h>
#include <math.h>

#define NN 50000
#define EE 800000
#define LL 4

typedef unsigned short u16;
typedef unsigned int u32;
typedef __attribute__((ext_vector_type(8))) short bf16x8;
typedef __attribute__((ext_vector_type(4))) float f32x4;

__device__ __forceinline__ float rlane(float v, int l) {
  return __int_as_float(__builtin_amdgcn_readlane(__float_as_int(v), l));
}
__device__ __forceinline__ u32 rlane_u32(u32 v, int l) {
  return (u32)__builtin_amdgcn_readlane((int)v, l);
}

__device__ __forceinline__ float matvec64(float xv, const float* __restrict__ w) {
  float a0 = 0.f, a1 = 0.f, a2 = 0.f, a3 = 0.f;
#pragma unroll
  for (int k = 0; k < 64; k += 4) {
    a0 = fmaf(rlane(xv, k + 0), w[k + 0], a0);
    a1 = fmaf(rlane(xv, k + 1), w[k + 1], a1);
    a2 = fmaf(rlane(xv, k + 2), w[k + 2], a2);
    a3 = fmaf(rlane(xv, k + 3), w[k + 3], a3);
  }
  return (a0 + a1) + (a2 + a3);
}

__device__ __forceinline__ float sigm(float x) { return 1.f / (1.f + __expf(-x)); }

__device__ __forceinline__ u16 f2b(float x) {
  u32 u = __float_as_uint(x);
  u32 r = (u + 0x7FFFu + ((u >> 16) & 1u)) >> 16;
  return (u16)r;
}
__device__ __forceinline__ float b2f(u16 b) { return __uint_as_float(((u32)b) << 16); }

__device__ __forceinline__ u16 f2h_(float x) {
  __half h = __float2half_rn(x);
  return *(u16*)&h;
}
__device__ __forceinline__ float h2f_(u16 b) {
  __half h = *(__half*)&b;
  return __half2float(h);
}

// ---------------- MFMA helpers (node-parallel, 16 nodes per wave) -----------
struct FragA { bf16x8 hi0, hi1, lo0, lo1; };

__device__ __forceinline__ void load_a(const float* __restrict__ base, int l, FragA& fa) {
  const int row = l & 15, quad = l >> 4;
  const float* src = base + (size_t)row * 64 + quad * 8;
  bf16x8 h0, h1, l0, l1;
#pragma unroll
  for (int j = 0; j < 8; ++j) {
    float x0 = src[j], x1 = src[32 + j];
    u16 a0 = f2b(x0), a1 = f2b(x1);
    h0[j] = (short)a0; h1[j] = (short)a1;
    l0[j] = (short)f2b(x0 - b2f(a0));
    l1[j] = (short)f2b(x1 - b2f(a1));
  }
  fa.hi0 = h0; fa.hi1 = h1; fa.lo0 = l0; fa.lo1 = l1;
}

__device__ __forceinline__ void gemm_acc(const FragA& fa, const float* __restrict__ W,
                                         int l, f32x4 acc[4]) {
  const int row = l & 15, quad = l >> 4;
#pragma unroll
  for (int cb = 0; cb < 4; ++cb) {
    f32x4 z = acc[cb];
#pragma unroll
    for (int kb = 0; kb < 2; ++kb) {
      bf16x8 bhi, blo;
      const float* wp = W + (size_t)(kb * 32 + quad * 8) * 64 + cb * 16 + row;
#pragma unroll
      for (int j = 0; j < 8; ++j) {
        float wv = wp[(size_t)j * 64];
        u16 aa = f2b(wv);
        bhi[j] = (short)aa;
        blo[j] = (short)f2b(wv - b2f(aa));
      }
      const bf16x8 ahi = kb ? fa.hi1 : fa.hi0;
      const bf16x8 alo = kb ? fa.lo1 : fa.lo0;
      z = __builtin_amdgcn_mfma_f32_16x16x32_bf16(ahi, bhi, z, 0, 0, 0);
      z = __builtin_amdgcn_mfma_f32_16x16x32_bf16(alo, bhi, z, 0, 0, 0);
      z = __builtin_amdgcn_mfma_f32_16x16x32_bf16(ahi, blo, z, 0, 0, 0);
    }
    acc[cb] = z;
  }
}

__device__ __forceinline__ void store16(const f32x4 acc[4], const float* __restrict__ bias,
                                        int l, float* __restrict__ out) {
  const int row = l & 15, quad = l >> 4;
#pragma unroll
  for (int cb = 0; cb < 4; ++cb) {
    int col = cb * 16 + row;
    float bv = bias[col];
#pragma unroll
    for (int r = 0; r < 4; ++r)
      out[(size_t)(quad * 4 + r) * 64 + col] = acc[cb][r] + bv;
  }
}

__global__ void k_t2(const float* __restrict__ h, const float* __restrict__ B1w,
                     int* __restrict__ flag) {
  int l = threadIdx.x;
  FragA fa;
  load_a(h, l, fa);
  f32x4 acc[4];
  acc[0] = (f32x4){0,0,0,0}; acc[1] = (f32x4){0,0,0,0};
  acc[2] = (f32x4){0,0,0,0}; acc[3] = (f32x4){0,0,0,0};
  gemm_acc(fa, B1w, l, acc);
  const int row = l & 15, quad = l >> 4;
  int ok = 1;
#pragma unroll
  for (int cb = 0; cb < 4; ++cb)
#pragma unroll
    for (int r = 0; r < 4; ++r) {
      int nrow = quad * 4 + r, col = cb * 16 + row;
      float ref = 0.f;
      for (int k = 0; k < 64; ++k) ref += h[nrow * 64 + k] * B1w[k * 64 + col];
      if (fabsf(acc[cb][r] - ref) > 3e-3f + 3e-3f * fabsf(ref)) ok = 0;
    }
  ok = __all(ok);
  if (l == 0) flag[0] = ok;
}

// ---------------- CSR build ----------------
__global__ void k_hist(const int* __restrict__ dst, int* __restrict__ counts) {
  int i = blockIdx.x * 256 + threadIdx.x;
  if (i < EE) atomicAdd(&counts[dst[i]], 1);
}

__global__ void k_scan(const int* __restrict__ counts, int* __restrict__ row_start,
                       int* __restrict__ cursor) {
  __shared__ int sd[1024];
  int tid = threadIdx.x;
  int running = 0;
  for (int basei = 0; basei < NN; basei += 1024) {
    int i = basei + tid;
    int v = (i < NN) ? counts[i] : 0;
    sd[tid] = v;
    __syncthreads();
    for (int ofs = 1; ofs < 1024; ofs <<= 1) {
      int t = (tid >= ofs) ? sd[tid - ofs] : 0;
      __syncthreads();
      sd[tid] += t;
      __syncthreads();
    }
    int incl = sd[tid];
    int total = sd[1023];
    if (i < NN) { int e = running + incl - v; row_start[i] = e; cursor[i] = e; }
    running += total;
    __syncthreads();
  }
  if (tid == 0) row_start[NN] = EE;
}

__global__ void k_scatter(const int* __restrict__ dst, const int* __restrict__ src,
                          const int* __restrict__ e_ids,
                          int* __restrict__ cursor, int* __restrict__ src_s,
                          int* __restrict__ eids_s) {
  int i = blockIdx.x * 256 + threadIdx.x;
  if (i < EE) {
    int d = dst[i];
    int pos = atomicAdd(&cursor[d], 1);
    src_s[pos] = src[i];
    eids_s[pos] = e_ids[i];
  }
}

__global__ void k_einit(const int* __restrict__ eids_s, const float* __restrict__ emb_e,
                        u16* __restrict__ e_sorted) {
  int idx = blockIdx.x * 256 + threadIdx.x;
  if (idx >= EE * 64) return;
  int ed = idx >> 6, f = idx & 63;
  e_sorted[idx] = f2h_(emb_e[eids_s[ed] * 64 + f]);
}

__global__ void k_ninit(const int* __restrict__ h_ids, const int* __restrict__ f_ids,
                        const float* __restrict__ emb_h, const float* __restrict__ emb_f,
                        float* __restrict__ h, float* __restrict__ p) {
  int idx = blockIdx.x * 256 + threadIdx.x;
  if (idx >= NN * 64) return;
  int n = idx >> 6, f = idx & 63;
  h[idx] = emb_h[h_ids[n] * 64 + f];
  p[idx] = emb_f[f_ids[n] * 64 + f];
}

// ---------------- k_Am: MFMA node GEMMs (runs iff flag=1) -------------------
// v & C2p packed as bf16 pair in one u32 (v = low16, C2p = high16): k_C's
// per-edge gather is 4B instead of 8B.
__global__ void __launch_bounds__(256) k_Am(
    int mode,
    float* __restrict__ h, float* __restrict__ p,
    float* __restrict__ hn, float* __restrict__ pn,
    const float* __restrict__ mu_h, const float* __restrict__ ir_h,
    const float* __restrict__ g_h, const float* __restrict__ b_h,
    const float* __restrict__ B1w, const float* __restrict__ B1b,
    const float* __restrict__ B2w, const float* __restrict__ B2b,
    const float* __restrict__ A1w, const float* __restrict__ A1b,
    const float* __restrict__ C1w, const float* __restrict__ C1b,
    const float* __restrict__ C2w, const float* __restrict__ C2b,
    const float* __restrict__ A2w, const float* __restrict__ A2b,
    float* __restrict__ B1h, float* __restrict__ B2h,
    u32* __restrict__ vc,
    const int* __restrict__ flag) {
  if (!flag[0]) return;
  const int f = threadIdx.x & 63;
  const int wv = threadIdx.x >> 6;
  const int base0 = (blockIdx.x * 4 + wv) * 16;
  if (base0 >= NN) return;

  if (mode) {
    float mu = mu_h[f], ir = ir_h[f], ga = g_h[f], be = b_h[f];
    for (int i = 0; i < 16; ++i) {
      int n = base0 + i;
      float hv = hn[(size_t)n * 64 + f];
      h[(size_t)n * 64 + f] += fmaxf(0.f, (hv - mu) * ir * ga + be);
      float pv = pn[(size_t)n * 64 + f];
      p[(size_t)n * 64 + f] += tanhf(pv);
    }
  }

  FragA fh, fq;
  load_a(h + (size_t)base0 * 64, f, fh);
  load_a(p + (size_t)base0 * 64, f, fq);
  f32x4 acc[4], accC[4];
#define ZERO(A) { A[0]=(f32x4){0,0,0,0}; A[1]=(f32x4){0,0,0,0}; \
                  A[2]=(f32x4){0,0,0,0}; A[3]=(f32x4){0,0,0,0}; }
  ZERO(acc); gemm_acc(fh, B1w, f, acc); store16(acc, B1b, f, B1h + (size_t)base0 * 64);
  ZERO(acc); gemm_acc(fh, B2w, f, acc); store16(acc, B2b, f, B2h + (size_t)base0 * 64);
  ZERO(acc); gemm_acc(fh, A1w, f, acc); store16(acc, A1b, f, hn + (size_t)base0 * 64);
  ZERO(acc); gemm_acc(fq, C1w, f, acc); store16(acc, C1b, f, pn + (size_t)base0 * 64);
  ZERO(accC); gemm_acc(fq, C2w, f, accC);                       // C2p
  ZERO(acc);  gemm_acc(fh, A2w, f, acc); gemm_acc(fq, A2w + 4096, f, acc);  // v
  {
    const int row = f & 15, quad = f >> 4;
#pragma unroll
    for (int cb = 0; cb < 4; ++cb) {
      int col = cb * 16 + row;
      float bv = A2b[col], cv = C2b[col];
#pragma unroll
      for (int r = 0; r < 4; ++r) {
        u32 pk = (u32)f2b(acc[cb][r] + bv) | ((u32)f2b(accC[cb][r] + cv) << 16);
        vc[(size_t)(base0 + quad * 4 + r) * 64 + col] = pk;
      }
    }
  }
#undef ZERO
}

// ---------------- k_Av: readlane fallback (runs iff flag=0) -----------------
__global__ void __launch_bounds__(256) k_Av(
    int mode,
    float* __restrict__ h, float* __restrict__ p,
    float* __restrict__ hn, float* __restrict__ pn,
    const float* __restrict__ mu_h, const float* __restrict__ ir_h,
    const float* __restrict__ g_h, const float* __restrict__ b_h,
    const float* __restrict__ B1w, const float* __restrict__ B1b,
    const float* __restrict__ B2w, const float* __restrict__ B2b,
    const float* __restrict__ A1w, const float* __restrict__ A1b,
    const float* __restrict__ C1w, const float* __restrict__ C1b,
    const float* __restrict__ C2w, const float* __restrict__ C2b,
    const float* __restrict__ A2w, const float* __restrict__ A2b,
    float* __restrict__ B1h, float* __restrict__ B2h,
    u32* __restrict__ vc,
    const int* __restrict__ flag) {
  if (flag[0]) return;
  const int f = threadIdx.x & 63;
  const int wv = threadIdx.x >> 6;
  const int base0 = (blockIdx.x * 4 + wv) * 16;
  if (base0 >= NN) return;

  if (mode) {
    float mu = mu_h[f], ir = ir_h[f], ga = g_h[f], be = b_h[f];
    for (int i = 0; i < 16; ++i) {
      int n = base0 + i;
      float hv = hn[n * 64 + f];
      h[n * 64 + f] += fmaxf(0.f, (hv - mu) * ir * ga + be);
      float pv = pn[n * 64 + f];
      p[n * 64 + f] += tanhf(pv);
    }
  }

  float w[64];
#define LOADW(WP) _Pragma("unroll") for (int k = 0; k < 64; ++k) w[k] = (WP)[k * 64 + f];
  LOADW(B1w);
  { float bb = B1b[f];
    for (int i = 0; i < 16; ++i) { int n = base0 + i;
      B1h[n * 64 + f] = matvec64(h[n * 64 + f], w) + bb; } }
  LOADW(B2w);
  { float bb = B2b[f];
    for (int i = 0; i < 16; ++i) { int n = base0 + i;
      B2h[n * 64 + f] = matvec64(h[n * 64 + f], w) + bb; } }
  LOADW(A1w);
  { float bb = A1b[f];
    for (int i = 0; i < 16; ++i) { int n = base0 + i;
      hn[n * 64 + f] = matvec64(h[n * 64 + f], w) + bb; } }
  LOADW(C1w);
  { float bb = C1b[f];
    for (int i = 0; i < 16; ++i) { int n = base0 + i;
      pn[n * 64 + f] = matvec64(p[n * 64 + f], w) + bb; } }
  LOADW(C2w);
  { float bb = C2b[f];
    for (int i = 0; i < 16; ++i) { int n = base0 + i;
      vc[(size_t)n * 64 + f] = ((u32)f2b(matvec64(p[n * 64 + f], w) + bb)) << 16; } }
  {
    float w2[64];
#pragma unroll
    for (int k = 0; k < 64; ++k) { w[k] = A2w[k * 64 + f]; w2[k] = A2w[(k + 64) * 64 + f]; }
    float bb = A2b[f];
    for (int i = 0; i < 16; ++i) { int n = base0 + i;
      float vval = matvec64(h[n * 64 + f], w) + matvec64(p[n * 64 + f], w2) + bb;
      vc[(size_t)n * 64 + f] |= (u32)f2b(vval); }
  }
#undef LOADW
}

// k_B: hat = e@B3 + B1h[src] + B2h[dst] + b3 ; sigma row-sum; BN-e stats.
// Packed-f16 __hfma2 matvec. MODE: 0 none; 1 deferred e-update + write;
// 2 deferred e-update in-register only (layer 3).
template <int SH, int MODE>
__global__ void __launch_bounds__(256) k_B(
    u16* __restrict__ e16, const float* __restrict__ B1h,
    const float* __restrict__ B2h, const int* __restrict__ src_s,
    const int* __restrict__ row_start,
    const float* __restrict__ B3w, const float* __restrict__ B3b,
    const float* __restrict__ mu_p, const float* __restrict__ ir_p,
    const float* __restrict__ g_p, const float* __restrict__ b_p,
    u16* __restrict__ hat, float* __restrict__ sum_sigma,
    float* __restrict__ eS1, float* __restrict__ eS2) {
  const int f = threadIdx.x & 63;
  const int wv = threadIdx.x >> 6;
  const int nb = (blockIdx.x * 4 + wv) * 4;
  if (nb >= NN) return;
  const int kk = f & 31;

  __half2 wpk[32];
#pragma unroll
  for (int k = 0; k < 32; ++k) {
    float w0 = B3w[(size_t)(2 * k) * 64 + f];
    float w1 = B3w[(size_t)(2 * k + 1) * 64 + f];
    wpk[k] = __floats2half2_rn(w0, w1);
  }
  const float bb = B3b[f];
  float a0 = 0.f, c0 = 0.f, a1 = 0.f, c1 = 0.f;
  if (MODE >= 1) {
    float m0 = mu_p[2 * kk], i0 = ir_p[2 * kk];
    float m1 = mu_p[2 * kk + 1], i1 = ir_p[2 * kk + 1];
    a0 = i0 * g_p[2 * kk];     c0 = b_p[2 * kk] - m0 * a0;
    a1 = i1 * g_p[2 * kk + 1]; c1 = b_p[2 * kk + 1] - m1 * a1;
  }
  float s1 = 0.f, s2 = 0.f;
  for (int i = 0; i < 4; ++i) {
    int n = nb + i;
    float b2 = B2h[(size_t)n * 64 + f] + bb;
    float ssum = 0.f;
    int t0 = row_start[n], t1 = row_start[n + 1];
    for (int t = t0; t < t1; ++t) {
      u32 xq = ((const u32*)e16)[(size_t)t * 32 + kk];
      if (MODE >= 1) {
        if (f < 32) {
          u32 hq = ((const u32*)hat)[(size_t)t * 32 + kk];
          float p0 = __uint_as_float(hq << 16);
          float p1 = __uint_as_float(hq & 0xffff0000u);
          __half2 ex = *(__half2*)&xq;
          float e0 = __low2float(ex)  + fmaxf(0.f, fmaf(p0, a0, c0));
          float e1 = __high2float(ex) + fmaxf(0.f, fmaf(p1, a1, c1));
          __half2 nq = __floats2half2_rn(e0, e1);
          xq = *(u32*)&nq;
          if (MODE == 1) ((u32*)e16)[(size_t)t * 32 + kk] = xq;
        }
      }
      int s = src_s[t];
      float g = B1h[(size_t)s * 64 + f];
      __half2 za = __float2half2_rn(0.f), zb = za, zc = za, zd = za;
#pragma unroll
      for (int k = 0; k < 32; k += 4) {
        u32 q0 = rlane_u32(xq, k + 0);
        u32 q1 = rlane_u32(xq, k + 1);
        u32 q2 = rlane_u32(xq, k + 2);
        u32 q3 = rlane_u32(xq, k + 3);
        za = __hfma2(*(__half2*)&q0, wpk[k + 0], za);
        zb = __hfma2(*(__half2*)&q1, wpk[k + 1], zb);
        zc = __hfma2(*(__half2*)&q2, wpk[k + 2], zc);
        zd = __hfma2(*(__half2*)&q3, wpk[k + 3], zd);
      }
      float dot = ((__low2float(za) + __high2float(za)) +
                   (__low2float(zb) + __high2float(zb))) +
                  ((__low2float(zc) + __high2float(zc)) +
                   (__low2float(zd) + __high2float(zd)));
      float acc = dot + b2 + g;
      if (SH) {
        u16 hb = f2b(acc);
        hat[(size_t)t * 64 + f] = hb;
        acc = b2f(hb);
      }
      float sg = sigm(acc);
      ssum += sg; s1 += acc; s2 += acc * acc;
    }
    sum_sigma[(size_t)n * 64 + f] = ssum;
  }
  int slot = (blockIdx.x & 255) * 64 + f;
  atomicAdd(&eS1[slot], s1);
  atomicAdd(&eS2[slot], s2);
}

// k_red: 256 threads (4-way strided partials + LDS combine)
__global__ void k_red(const float* __restrict__ S1, const float* __restrict__ S2,
                      float cnt, float* __restrict__ mu, float* __restrict__ ir) {
  __shared__ float p1[256], p2[256];
  int tid = threadIdx.x;
  int f = tid & 63, g = tid >> 6;
  float a = 0.f, b = 0.f;
  for (int j = g; j < 256; j += 4) { a += S1[j * 64 + f]; b += S2[j * 64 + f]; }
  p1[tid] = a; p2[tid] = b;
  __syncthreads();
  if (tid < 64) {
    a = (p1[tid] + p1[tid + 64]) + (p1[tid + 128] + p1[tid + 192]);
    b = (p2[tid] + p2[tid + 64]) + (p2[tid + 128] + p2[tid + 192]);
    float m = a / cnt;
    float var = fmaxf(b / cnt - m * m, 0.f);
    mu[f] = m;
    ir[f] = rsqrtf(var + 1e-5f);
  }
}

// k_C: eta, single u32 (bf16 pair) gather per (edge,feature), BN-h stats.
template <int SH, int LAST>
__global__ void __launch_bounds__(256) k_C(
    const u16* __restrict__ hat, u16* __restrict__ e_sorted,
    const float* __restrict__ B1h, const float* __restrict__ B2h,
    const float* __restrict__ B3w, const float* __restrict__ B3b,
    const u32* __restrict__ vc,
    const int* __restrict__ src_s, const int* __restrict__ row_start,
    const float* __restrict__ sum_sigma,
    float* __restrict__ hn, float* __restrict__ pn,
    const float* __restrict__ mu_e, const float* __restrict__ ir_e,
    const float* __restrict__ g_e, const float* __restrict__ b_e,
    float* __restrict__ hS1, float* __restrict__ hS2) {
  const int f = threadIdx.x & 63;
  const int wv = threadIdx.x >> 6;
  const int n = blockIdx.x * 4 + wv;
  if (n >= NN) return;
  float w[64];
  float bb = 0.f;
  if (!SH) {
#pragma unroll
    for (int k = 0; k < 64; ++k) w[k] = B3w[k * 64 + f];
    bb = B3b[f];
  }
  float mu = mu_e[f], ir = ir_e[f], ga = g_e[f], be = b_e[f];
  float inv = 1.f / (sum_sigma[n * 64 + f] + 1e-6f);
  float ahv = 0.f, ahp = 0.f;
  int t0 = row_start[n], t1 = row_start[n + 1];
  int t = t0;
  if (SH) {
    for (; t + 4 <= t1; t += 4) {
      size_t s0 = (size_t)src_s[t + 0] * 64 + f, s1 = (size_t)src_s[t + 1] * 64 + f;
      size_t s2 = (size_t)src_s[t + 2] * 64 + f, s3 = (size_t)src_s[t + 3] * 64 + f;
      float hv0 = b2f(hat[(size_t)(t + 0) * 64 + f]);
      float hv1 = b2f(hat[(size_t)(t + 1) * 64 + f]);
      float hv2 = b2f(hat[(size_t)(t + 2) * 64 + f]);
      float hv3 = b2f(hat[(size_t)(t + 3) * 64 + f]);
      u32 q0 = vc[s0], q1 = vc[s1], q2 = vc[s2], q3 = vc[s3];
      float et0 = sigm(hv0) * inv, et1 = sigm(hv1) * inv;
      float et2 = sigm(hv2) * inv, et3 = sigm(hv3) * inv;
      ahv += et0 * b2f((u16)(q0 & 0xffff)) + et1 * b2f((u16)(q1 & 0xffff)) +
             et2 * b2f((u16)(q2 & 0xffff)) + et3 * b2f((u16)(q3 & 0xffff));
      if (!LAST)
        ahp += et0 * b2f((u16)(q0 >> 16)) + et1 * b2f((u16)(q1 >> 16)) +
               et2 * b2f((u16)(q2 >> 16)) + et3 * b2f((u16)(q3 >> 16));
    }
  }
  for (; t < t1; ++t) {
    size_t s = (size_t)src_s[t] * 64 + f;
    float ev = 0.f;
    if (!SH) ev = h2f_(e_sorted[(size_t)t * 64 + f]);
    float hatv;
    if (SH) hatv = b2f(hat[(size_t)t * 64 + f]);
    else    hatv = matvec64(ev, w) + bb + B2h[n * 64 + f] + B1h[((size_t)src_s[t]) * 64 + f];
    float eta = sigm(hatv) * inv;
    u32 q = vc[s];
    ahv = fmaf(eta, b2f((u16)(q & 0xffff)), ahv);
    if (!LAST) {
      ahp = fmaf(eta, b2f((u16)(q >> 16)), ahp);
      if (!SH)
        e_sorted[(size_t)t * 64 + f] = f2h_(ev + fmaxf(0.f, (hatv - mu) * ir * ga + be));
    }
  }
  float hv = hn[n * 64 + f] + ahv; hn[n * 64 + f] = hv;
  if (!LAST) pn[n * 64 + f] += ahp;
  int slot = (blockIdx.x & 255) * 64 + f;
  atomicAdd(&hS1[slot], hv);
  atomicAdd(&hS2[slot], hv * hv);
}

__global__ void __launch_bounds__(256) k_F1(
    const float* __restrict__ hn, const float* __restrict__ h,
    const float* __restrict__ mu, const float* __restrict__ ir,
    const float* __restrict__ ga, const float* __restrict__ be,
    float* __restrict__ hsum) {
  int f = threadIdx.x & 63, wv = threadIdx.x >> 6;
  float m = mu[f], r = ir[f], g = ga[f], b = be[f];
  float ps = 0.f;
  for (int n = blockIdx.x * 4 + wv; n < NN; n += gridDim.x * 4)
    ps += h[n * 64 + f] + fmaxf(0.f, (hn[n * 64 + f] - m) * r * g + b);
  atomicAdd(&hsum[f], ps);
}

__global__ void k_F2(const float* __restrict__ hsum,
                     const float* __restrict__ w0, const float* __restrict__ b0,
                     const float* __restrict__ w1, const float* __restrict__ b1,
                     const float* __restrict__ w2, const float* __restrict__ b2,
                     float* __restrict__ out) {
  __shared__ float hg[64]; __shared__ float y0[32]; __shared__ float y1[16];
  int t = threadIdx.x;
  hg[t] = hsum[t] * (1.f / (float)NN);
  __syncthreads();
  if (t < 32) { float a = b0[t];
    for (int k = 0; k < 64; ++k) a = fmaf(hg[k], w0[k * 32 + t], a);
    y0[t] = fmaxf(a, 0.f); }
  __syncthreads();
  if (t < 16) { float a = b1[t];
    for (int k = 0; k < 32; ++k) a = fmaf(y0[k], w1[k * 16 + t], a);
    y1[t] = fmaxf(a, 0.f); }
  __syncthreads();
  if (t == 0) { float a = b2[0];
    for (int k = 0; k < 16; ++k) a = fmaf(y1[k], w2[k], a);
    out[0] = a; }
}

__global__ void k_report(float* out, float v) { out[0] = v; }

extern "C" void kernel_launch(void* const* d_in, const int* in_sizes, int n_in,
                              void* d_out, int out_size, void* d_ws, size_t ws_size,
                              hipStream_t stream) {
  (void)in_sizes; (void)n_in; (void)out_size;
  const int* h_ids = (const int*)d_in[0];
  const int* e_ids = (const int*)d_in[1];
  const int* f_ids = (const int*)d_in[2];
  const int* src   = (const int*)d_in[3];
  const int* dst   = (const int*)d_in[4];
  const float* emb_h = (const float*)d_in[5];
  const float* emb_e = (const float*)d_in[6];
  const float* emb_f = (const float*)d_in[7];
  const float* A1_w = (const float*)d_in[8];  const float* A1_b = (const float*)d_in[9];
  const float* A2_w = (const float*)d_in[10]; const float* A2_b = (const float*)d_in[11];
  const float* B1_w = (const float*)d_in[12]; const float* B1_b = (const float*)d_in[13];
  const float* B2_w = (const float*)d_in[14]; const float* B2_b = (const float*)d_in[15];
  const float* B3_w = (const float*)d_in[16]; const float* B3_b = (const float*)d_in[17];
  const float* C1_w = (const float*)d_in[18]; const float* C1_b = (const float*)d_in[19];
  const float* C2_w = (const float*)d_in[20]; const float* C2_b = (const float*)d_in[21];
  const float* bn_h_g = (const float*)d_in[22]; const float* bn_h_b = (const float*)d_in[23];
  const float* bn_e_g = (const float*)d_in[24]; const float* bn_e_b = (const float*)d_in[25];
  const float* mlp_w0 = (const float*)d_in[26]; const float* mlp_b0 = (const float*)d_in[27];
  const float* mlp_w1 = (const float*)d_in[28]; const float* mlp_b1 = (const float*)d_in[29];
  const float* mlp_w2 = (const float*)d_in[30]; const float* mlp_b2 = (const float*)d_in[31];

  auto pad = [](size_t b) { return (b + 255) & ~(size_t)255; };
  const size_t sz_e    = pad((size_t)EE * 64 * 2);   // f16 edge state
  const size_t sz_node = pad((size_t)NN * 64 * 4);   // fp32 node buffer
  const size_t sz_cnt  = pad((size_t)NN * 4);
  const size_t sz_row  = pad((size_t)(NN + 1) * 4);
  const size_t sz_ei   = pad((size_t)EE * 4);
  const size_t sz_stat = pad((size_t)LL * 2 * 256 * 64 * 4);
  const size_t sz_vec  = pad(64 * 4);

  size_t base_need = sz_e + 8 * sz_node + 2 * sz_cnt + sz_row + 2 * sz_ei +
                     2 * sz_stat + 6 * sz_vec;
  bool store_hat = (base_need + sz_e) <= ws_size;
  if (base_need > ws_size) {
    k_report<<<1, 1, 0, stream>>>((float*)d_out, (float)(ws_size >> 20) + 0.125f);
    return;
  }

  char* cur = (char*)d_ws;
  auto alloc = [&](size_t bytes) -> char* { char* r = cur; cur += bytes; return r; };
  u16* e_sorted = (u16*)alloc(sz_e);
  u16* hat      = store_hat ? (u16*)alloc(sz_e) : (u16*)e_sorted;  // dummy if unused
  float* h    = (float*)alloc(sz_node);
  float* p    = (float*)alloc(sz_node);
  float* hn   = (float*)alloc(sz_node);
  float* pn   = (float*)alloc(sz_node);
  float* B1h  = (float*)alloc(sz_node);
  float* B2h  = (float*)alloc(sz_node);
  u32*   vc   = (u32*)alloc(sz_node);    // packed bf16 {v, C2p}
  float* ssig = (float*)alloc(sz_node);
  int* counts    = (int*)alloc(sz_cnt);
  int* cursor    = (int*)alloc(sz_cnt);
  int* row_start = (int*)alloc(sz_row);
  int* src_s     = (int*)alloc(sz_ei);
  int* eids_s    = (int*)alloc(sz_ei);
  float* estats = (float*)alloc(sz_stat);
  float* hstats = (float*)alloc(sz_stat);
  float* hsum   = (float*)alloc(sz_vec);
  float* mu_h = (float*)alloc(sz_vec);
  float* ir_h = (float*)alloc(sz_vec);
  float* mu_e = (float*)alloc(sz_vec);
  float* ir_e = (float*)alloc(sz_vec);
  int* flag  = (int*)alloc(sz_vec);

  hipMemsetAsync(counts, 0, sz_cnt, stream);
  hipMemsetAsync(estats, 0, 2 * sz_stat + sz_vec, stream);  // estats + hstats + hsum

  k_hist<<<(EE + 255) / 256, 256, 0, stream>>>(dst, counts);
  k_scan<<<1, 1024, 0, stream>>>(counts, row_start, cursor);
  k_scatter<<<(EE + 255) / 256, 256, 0, stream>>>(dst, src, e_ids, cursor, src_s, eids_s);
  k_einit<<<(EE * 64) / 256, 256, 0, stream>>>(eids_s, emb_e, e_sorted);
  k_ninit<<<(NN * 64 + 255) / 256, 256, 0, stream>>>(h_ids, f_ids, emb_h, emb_f, h, p);
  k_t2<<<1, 64, 0, stream>>>(h, B1_w, flag);

  const int STAT = 2 * 256 * 64;
  const int GB = (NN + 15) / 16, GC = (NN + 3) / 4;
  for (int i = 0; i < LL; ++i) {
    if (i > 0) {
      k_red<<<1, 256, 0, stream>>>(hstats + (i - 1) * STAT,
                                   hstats + (i - 1) * STAT + 256 * 64, (float)NN, mu_h, ir_h);
    }
    const float* gh = bn_h_g + (i > 0 ? (i - 1) * 64 : 0);
    const float* bh = bn_h_b + (i > 0 ? (i - 1) * 64 : 0);
    k_Am<<<(NN + 63) / 64, 256, 0, stream>>>(
        (i > 0) ? 1 : 0, h, p, hn, pn, mu_h, ir_h, gh, bh,
        B1_w + i * 4096, B1_b + i * 64, B2_w + i * 4096, B2_b + i * 64,
        A1_w + i * 4096, A1_b + i * 64, C1_w + i * 4096, C1_b + i * 64,
        C2_w + i * 4096, C2_b + i * 64, A2_w + i * 8192, A2_b + i * 64,
        B1h, B2h, vc, flag);
    k_Av<<<(NN + 63) / 64, 256, 0, stream>>>(
        (i > 0) ? 1 : 0, h, p, hn, pn, mu_h, ir_h, gh, bh,
        B1_w + i * 4096, B1_b + i * 64, B2_w + i * 4096, B2_b + i * 64,
        A1_w + i * 4096, A1_b + i * 64, C1_w + i * 4096, C1_b + i * 64,
        C2_w + i * 4096, C2_b + i * 64, A2_w + i * 8192, A2_b + i * 64,
        B1h, B2h, vc, flag);
    const float* gp = bn_e_g + (i > 0 ? (i - 1) * 64 : 0);
    const float* bp = bn_e_b + (i > 0 ? (i - 1) * 64 : 0);
    if (store_hat) {
      if (i == 0)
        k_B<1, 0><<<GB, 256, 0, stream>>>(
            e_sorted, B1h, B2h, src_s, row_start, B3_w + i * 4096, B3_b + i * 64,
            mu_e, ir_e, gp, bp, hat, ssig,
            estats + i * STAT, estats + i * STAT + 256 * 64);
      else if (i < LL - 1)
        k_B<1, 1><<<GB, 256, 0, stream>>>(
            e_sorted, B1h, B2h, src_s, row_start, B3_w + i * 4096, B3_b + i * 64,
            mu_e, ir_e, gp, bp, hat, ssig,
            estats + i * STAT, estats + i * STAT + 256 * 64);
      else
        k_B<1, 2><<<GB, 256, 0, stream>>>(
            e_sorted, B1h, B2h, src_s, row_start, B3_w + i * 4096, B3_b + i * 64,
            mu_e, ir_e, gp, bp, hat, ssig,
            estats + i * STAT, estats + i * STAT + 256 * 64);
    } else {
      k_B<0, 0><<<GB, 256, 0, stream>>>(
          e_sorted, B1h, B2h, src_s, row_start, B3_w + i * 4096, B3_b + i * 64,
          mu_e, ir_e, gp, bp, hat, ssig,
          estats + i * STAT, estats + i * STAT + 256 * 64);
    }
    if (!store_hat || i < LL - 1)
      k_red<<<1, 256, 0, stream>>>(estats + i * STAT, estats + i * STAT + 256 * 64,
                                   (float)EE, mu_e, ir_e);
    bool lastL = (i == LL - 1);
    if (store_hat) {
      if (lastL)
        k_C<1, 1><<<GC, 256, 0, stream>>>(
            hat, e_sorted, B1h, B2h, B3_w + i * 4096, B3_b + i * 64, vc,
            src_s, row_start, ssig, hn, pn, mu_e, ir_e,
            bn_e_g + i * 64, bn_e_b + i * 64,
            hstats + i * STAT, hstats + i * STAT + 256 * 64);
      else
        k_C<1, 0><<<GC, 256, 0, stream>>>(
            hat, e_sorted, B1h, B2h, B3_w + i * 4096, B3_b + i * 64, vc,
            src_s, row_start, ssig, hn, pn, mu_e, ir_e,
            bn_e_g + i * 64, bn_e_b + i * 64,
            hstats + i * STAT, hstats + i * STAT + 256 * 64);
    } else {
      k_C<0, 0><<<GC, 256, 0, stream>>>(
          hat, e_sorted, B1h, B2h, B3_w + i * 4096, B3_b + i * 64, vc,
          src_s, row_start, ssig, hn, pn, mu_e, ir_e,
          bn_e_g + i * 64, bn_e_b + i * 64,
          hstats + i * STAT, hstats + i * STAT + 256 * 64);
    }
  }
  k_red<<<1, 256, 0, stream>>>(hstats + 3 * STAT, hstats + 3 * STAT + 256 * 64,
                               (float)NN, mu_h, ir_h);
  k_F1<<<512, 256, 0, stream>>>(hn, h, mu_h, ir_h, bn_h_g + 3 * 64, bn_h_b + 3 * 64, hsum);
  k_F2<<<1, 64, 0, stream>>>(hsum, mlp_w0, mlp_b0, mlp_w1, mlp_b1, mlp_w2, mlp_b2,
                             (float*)d_out);
}